// Round 3
// baseline (611.677 us; speedup 1.0000x reference)
//
#include <hip/hip_runtime.h>

// ChunkedSelfAttention (RoPE + per-chunk causal SDPA), MI355X gfx950.
// R3: pure-f16 MFMA path; 256-thread blocks (4 waves), 32-key tiles,
// 3 blocks/CU; conflict-free swizzled LDS; paired q-strips (uniform blocks);
// double-buffered staging with K register prefetch; T13 deferred rescale.

typedef __attribute__((ext_vector_type(2)))  float     f32x2;
typedef __attribute__((ext_vector_type(4)))  float     f32x4;
typedef __attribute__((ext_vector_type(16))) float     f32x16;
typedef __attribute__((ext_vector_type(8)))  _Float16  f16x8;
typedef unsigned int   u32;
typedef unsigned short u16;
typedef __attribute__((ext_vector_type(4))) unsigned int u32x4;

#define MFMA(a, b, c) __builtin_amdgcn_mfma_f32_32x32x16_f16(a, b, c, 0, 0, 0)

constexpr int Ll = 4096;
// scale(1/sqrt(128)) * log2(e): softmax in base-2 (exp2) domain.
constexpr float QSCALE = 0.08838834764831845f * 1.4426950408889634f;

// per-buffer LDS: KH [32 rows][256 B] (swizzled, no pad) = 8192 B;
//                 VT [128 rows][80 B]  (16 dw data + 4 pad, swizzled) = 10240 B.
#define VT_OFF 8192
#define BUF_SZ 18432

__device__ __forceinline__ f16x8 ld_f16x8(const void* p) { f16x8 v; __builtin_memcpy(&v, p, 16); return v; }
__device__ __forceinline__ f32x4 ld_f32x4(const void* p) { f32x4 v; __builtin_memcpy(&v, p, 16); return v; }
__device__ __forceinline__ f32x2 ld_f32x2(const void* p) { f32x2 v; __builtin_memcpy(&v, p, 8);  return v; }

__device__ __forceinline__ u32 packh(_Float16 a, _Float16 b) {
  return (u32)__builtin_bit_cast(u16, a) | ((u32)__builtin_bit_cast(u16, b) << 16);
}

// ---- cos/sin table: tab[t*128 + 2*hid] = {cos, sin}, ang = (t+start)*inv_freq ----
__global__ void rope_table_k(const int* __restrict__ startp, float* __restrict__ tab) {
  int idx = blockIdx.x * 256 + threadIdx.x;         // 4096*64 entries
  int t = idx >> 6, hid = idx & 63;
  float a = (float)hid * (-0.14391156831212878f);   // -ln(1e4)/64
  float invf = expf(a);
  float ang = (float)(t + startp[0]) * invf;
  tab[2 * idx]     = cosf(ang);
  tab[2 * idx + 1] = sinf(ang);
}

__global__ __launch_bounds__(256, 3)
void chunked_attn_k(const float* __restrict__ Qg, const float* __restrict__ Kg,
                    const float* __restrict__ Vg, float* __restrict__ Og,
                    const float* __restrict__ tab) {
  __shared__ __align__(16) unsigned char smem[2 * BUF_SZ];

  const int bx  = blockIdx.x;
  const int p   = bx & 3;                // strip pair: (7-p, p)
  const int h   = (bx >> 2) & 15;
  const int c   = (bx >> 6) & 3;
  const int b   = bx >> 8;
  const int tid = threadIdx.x;
  const int w   = tid >> 6;              // wave 0..3
  const int lane= tid & 63;
  const int l31 = lane & 31;
  const int lg2 = lane >> 5;

  const size_t cbase = (size_t)(b * Ll + c * 1024);   // token base of chunk
  const size_t hoff  = (size_t)h * 128;
  const int tb = c * 1024;                            // tab row base of chunk

  // K register prefetch (V + cos/sin are loaded batched inside xform)
  f32x2 pka[4], pkb[4];

  auto issue = [&](int j) {
    const float* kb_ = Kg + (cbase + (size_t)j * 32) * 2048 + hoff;
    #pragma unroll
    for (int it = 0; it < 4; ++it) {
      int kk = 8 * it + 2 * w + lg2;                 // 0..31 bijective
      const float* kr = kb_ + (size_t)kk * 2048 + 2 * l31;
      pka[it] = ld_f32x2(kr);
      pkb[it] = ld_f32x2(kr + 64);
    }
  };

  auto xform = [&](int j, unsigned char* buf) {
    u32* KHu = (u32*)buf;
    u32* VTu = (u32*)(buf + VT_OFF);
    // batch-issue V loads (8) and cos/sin loads (4) first
    const float* vb_ = Vg + (cbase + (size_t)j * 32) * 2048 + hoff;
    f32x2 va[4], vvb[4];
    f32x4 cs[4];
    #pragma unroll
    for (int it = 0; it < 4; ++it) {
      int kp  = ((lane >> 4) & 3) | (it << 2);       // dword k-col 0..15
      int dvp = (lane & 15) | (w << 4);              // dv pair 0..63
      const float* vr = vb_ + (size_t)(2 * kp) * 2048 + 2 * dvp;
      va[it]  = ld_f32x2(vr);
      vvb[it] = ld_f32x2(vr + 2048);
    }
    #pragma unroll
    for (int it = 0; it < 4; ++it) {
      int kk = 8 * it + 2 * w + lg2;
      cs[it] = ld_f32x4(tab + (size_t)(tb + j * 32 + kk) * 128 + 4 * l31);
    }
    // K: rope + f16 pack, swizzled store (col ^= (row&7)<<2) — bank-conflict-free
    #pragma unroll
    for (int it = 0; it < 4; ++it) {
      int kk = 8 * it + 2 * w + lg2;
      f32x2 a = pka[it], bb = pkb[it];
      float ar0 = a.x * cs[it].x - bb.x * cs[it].y;
      float br0 = bb.x * cs[it].x + a.x * cs[it].y;
      float ar1 = a.y * cs[it].z - bb.y * cs[it].w;
      float br1 = bb.y * cs[it].z + a.y * cs[it].w;
      int sw = (kk & 7) << 2;
      KHu[kk * 64 + ((l31) ^ sw)]      = packh((_Float16)ar0, (_Float16)ar1);
      KHu[kk * 64 + 32 + ((l31) ^ sw)] = packh((_Float16)br0, (_Float16)br1);
    }
    // V^T: f16 pack, swizzled store (col ^= ((row>>2)&3)<<2), 80 B row stride
    #pragma unroll
    for (int it = 0; it < 4; ++it) {
      int kp  = ((lane >> 4) & 3) | (it << 2);
      int dvp = (lane & 15) | (w << 4);
      int dv0 = 2 * dvp;
      VTu[dv0 * 20 + (kp ^ (((dv0 >> 2) & 3) << 2))] =
          packh((_Float16)va[it].x, (_Float16)vvb[it].x);
      VTu[(dv0 + 1) * 20 + (kp ^ ((((dv0 + 1) >> 2) & 3) << 2))] =
          packh((_Float16)va[it].y, (_Float16)vvb[it].y);
    }
  };

  #pragma unroll 1
  for (int sp = 0; sp < 2; ++sp) {
    const int qi = sp ? p : (7 - p);          // heavy strip first
    const int qrow = qi * 128 + w * 32 + l31; // chunk-local q row (lane's column)

    // ---------- Q prologue: load, rope, scale, f16 ----------
    const float* qbase = Qg + (cbase + qrow) * 2048 + hoff;
    float xq[8][8];
    #pragma unroll
    for (int ds = 0; ds < 8; ++ds) {
      const float* ptr = qbase + ds * 16 + lg2 * 8;
      f32x4 v0 = ld_f32x4(ptr);
      f32x4 v1 = ld_f32x4(ptr + 4);
      xq[ds][0]=v0.x; xq[ds][1]=v0.y; xq[ds][2]=v0.z; xq[ds][3]=v0.w;
      xq[ds][4]=v1.x; xq[ds][5]=v1.y; xq[ds][6]=v1.z; xq[ds][7]=v1.w;
    }
    const float* trowq = tab + (size_t)(tb + qrow) * 128 + lg2 * 16;
    #pragma unroll
    for (int ds = 0; ds < 4; ++ds) {
      #pragma unroll
      for (int i2 = 0; i2 < 4; ++i2) {
        f32x4 cs = ld_f32x4(trowq + ds * 32 + i2 * 4);  // c0,s0,c1,s1
        int i0 = 2 * i2;
        float a0 = xq[ds][i0],     b0 = xq[ds + 4][i0];
        xq[ds][i0]     = a0 * cs.x - b0 * cs.y;
        xq[ds + 4][i0] = b0 * cs.x + a0 * cs.y;
        float a1 = xq[ds][i0 + 1], b1 = xq[ds + 4][i0 + 1];
        xq[ds][i0 + 1]     = a1 * cs.z - b1 * cs.w;
        xq[ds + 4][i0 + 1] = b1 * cs.z + a1 * cs.w;
      }
    }
    f16x8 qh[8];
    #pragma unroll
    for (int ds = 0; ds < 8; ++ds)
      #pragma unroll
      for (int i = 0; i < 8; ++i)
        qh[ds][i] = (_Float16)(xq[ds][i] * QSCALE);

    // ---------- state ----------
    f32x16 O[4];
    #pragma unroll
    for (int n = 0; n < 4; ++n) O[n] = (f32x16)0.0f;
    float m2 = -1e30f, lsum = 0.0f;
    const int jmaxw = 4 * qi + w;     // wave's diagonal tile
    const int nt    = 4 * (qi + 1);

    issue(0);
    xform(0, smem);
    __syncthreads();

    for (int j = 0; j < nt; ++j) {
      unsigned char* bufc = smem + (size_t)(j & 1) * BUF_SZ;
      const bool more = (j + 1 < nt);
      if (more) issue(j + 1);          // K loads fly under compute

      if (j <= jmaxw) {
        // ---- QK^T (swapped): S^T[k][q] = K . Q^T ----
        f32x16 S = (f32x16)0.0f;
        const unsigned char* khb = bufc + (size_t)l31 * 256;
        const int ksw = (l31 & 7) << 2;
        #pragma unroll
        for (int ds = 0; ds < 8; ++ds) {
          int col = (ds * 8 + lg2 * 4) ^ ksw;
          f16x8 kh = ld_f16x8(khb + col * 4);
          S = MFMA(kh, qh[ds], S);
        }

        // ---- causal mask (diagonal tile only; tile width == wave q width) ----
        if (j == jmaxw) {
          #pragma unroll
          for (int r = 0; r < 16; ++r) {
            int crow = (r & 3) + 8 * (r >> 2) + 4 * lg2;
            if (crow > l31) S[r] = -1e30f;
          }
        }

        // ---- online softmax (base-2), T13 deferred rescale ----
        float tm = S[0];
        #pragma unroll
        for (int r = 1; r < 16; ++r) tm = fmaxf(tm, S[r]);
        tm = fmaxf(tm, __shfl_xor(tm, 32));
        if (!__all(tm <= m2 + 8.0f)) {
          float m2n = fmaxf(m2, tm);
          float fac = exp2f(m2 - m2n);
          lsum *= fac;
          #pragma unroll
          for (int r = 0; r < 16; ++r) {
            int rq = (r & 3) + 8 * (r >> 2) + 4 * lg2;
            float fr = __shfl(fac, rq);
            O[0][r] *= fr; O[1][r] *= fr; O[2][r] *= fr; O[3][r] *= fr;
          }
          m2 = m2n;
        }
        u32 U[8];
        float ps = 0.0f;
        #pragma unroll
        for (int t = 0; t < 8; ++t) {
          float e0 = exp2f(S[2 * t]     - m2);
          float e1 = exp2f(S[2 * t + 1] - m2);
          U[t] = packh((_Float16)e0, (_Float16)e1);
          ps += e0 + e1;
        }
        ps += __shfl_xor(ps, 32);
        lsum += ps;

        // ---- PV: P fragment in-register via permlane32_swap ----
        const unsigned char* vtb = bufc + VT_OFF;
        #pragma unroll
        for (int ks = 0; ks < 2; ++ks) {
          u32 a0 = U[4 * ks + 0], a1 = U[4 * ks + 1];
          u32 b0 = U[4 * ks + 2], b1 = U[4 * ks + 3];
          asm("v_permlane32_swap_b32 %0, %1" : "+v"(a0), "+v"(b0));
          asm("v_permlane32_swap_b32 %0, %1" : "+v"(a1), "+v"(b1));
          u32x4 t4; t4.x = a0; t4.y = a1; t4.z = b0; t4.w = b1;
          f16x8 pa = __builtin_bit_cast(f16x8, t4);
          #pragma unroll
          for (int n = 0; n < 4; ++n) {
            int row = 32 * n + l31;
            int col = (ks * 8 + lg2 * 4) ^ (((row >> 2) & 3) << 2);
            f16x8 vh = ld_f16x8(vtb + (size_t)row * 80 + col * 4);
            O[n] = MFMA(pa, vh, O[n]);
          }
        }
      }

      if (more) xform(j + 1, smem + (size_t)((j + 1) & 1) * BUF_SZ);
      __syncthreads();
    }

    // ---------- epilogue ----------
    float inv = 1.0f / lsum;
    #pragma unroll
    for (int r = 0; r < 16; ++r) {
      int rq = (r & 3) + 8 * (r >> 2) + 4 * lg2;
      float fi = __shfl(inv, rq);
      float* orow = Og + (cbase + qi * 128 + w * 32 + rq) * 2048 + hoff + l31;
      orow[0]  = O[0][r] * fi;
      orow[32] = O[1][r] * fi;
      orow[64] = O[2][r] * fi;
      orow[96] = O[3][r] * fi;
    }
  }
}

extern "C" void kernel_launch(void* const* d_in, const int* in_sizes, int n_in,
                              void* d_out, int out_size, void* d_ws, size_t ws_size,
                              hipStream_t stream) {
  const float* q = (const float*)d_in[0];
  const float* k = (const float*)d_in[1];
  const float* v = (const float*)d_in[2];
  const int* start = (const int*)d_in[3];
  float* out = (float*)d_out;
  float* tab = (float*)d_ws;     // 4096*64*2 floats = 2 MB

  rope_table_k<<<dim3(1024), dim3(256), 0, stream>>>(start, tab);
  chunked_attn_k<<<dim3(1024), dim3(256), 0, stream>>>(q, k, v, out, tab);
}

// Round 4
// 315.713 us; speedup vs baseline: 1.9374x; 1.9374x over previous
//
#include <hip/hip_runtime.h>

// ChunkedSelfAttention (RoPE + per-chunk causal SDPA), MI355X gfx950.
// R4: 8-wave blocks, 64-key tiles, full register prefetch (K+V) one tile
// ahead, 1 barrier/tile, LDS strides giving provable 2-way (free) bank
// access on all hot paths, in-register P via permlane32_swap, T13 deferred
// rescale, T5 setprio, paired q-strips (uniform 20 tiles/block).

typedef __attribute__((ext_vector_type(2)))  float     f32x2;
typedef __attribute__((ext_vector_type(4)))  float     f32x4;
typedef __attribute__((ext_vector_type(16))) float     f32x16;
typedef __attribute__((ext_vector_type(8)))  _Float16  f16x8;
typedef unsigned int   u32;
typedef unsigned short u16;
typedef __attribute__((ext_vector_type(4))) unsigned int u32x4;

#define MFMA(a, b, c) __builtin_amdgcn_mfma_f32_32x32x16_f16(a, b, c, 0, 0, 0)

constexpr int Ll = 4096;
// scale(1/sqrt(128)) * log2(e): softmax in base-2 (exp2) domain.
constexpr float QSCALE = 0.08838834764831845f * 1.4426950408889634f;

// LDS (dwords): K [64 rows][66 dw] (264B rows: 8B-aligned, bank=(2k+c)%32),
//               V^T [128 rows][34 dw] (136B rows, bank=(2dv+c)%32).
#define KSTR 66
#define VSTR 34
#define KBUF (64 * KSTR)        // 4224 dw
#define VBUF (128 * VSTR)       // 4352 dw
#define STG  (KBUF + VBUF)      // 8576 dw per stage; 2 stages = 68608 B

__device__ __forceinline__ f32x4 ld_f32x4(const void* p) { f32x4 v; __builtin_memcpy(&v, p, 16); return v; }
__device__ __forceinline__ f32x2 ld_f32x2(const void* p) { f32x2 v; __builtin_memcpy(&v, p, 8);  return v; }
// 8 f16 fragment = two ds_read_b64 at dw, dw+2 (both 8B-aligned by layout)
__device__ __forceinline__ f16x8 ld_frag(const u32* dwp) {
  f16x8 v;
  __builtin_memcpy(&v, dwp, 8);
  __builtin_memcpy(((char*)&v) + 8, dwp + 2, 8);
  return v;
}

__device__ __forceinline__ u32 packh(_Float16 a, _Float16 b) {
  return (u32)__builtin_bit_cast(u16, a) | ((u32)__builtin_bit_cast(u16, b) << 16);
}

// ---- cos/sin table: tab[t*128 + 2*hid] = {cos, sin}, ang = (t+start)*inv_freq ----
__global__ void rope_table_k(const int* __restrict__ startp, float* __restrict__ tab) {
  int idx = blockIdx.x * 256 + threadIdx.x;         // 4096*64 entries
  int t = idx >> 6, hid = idx & 63;
  float a = (float)hid * (-0.14391156831212878f);   // -ln(1e4)/64
  float invf = expf(a);
  float ang = (float)(t + startp[0]) * invf;
  tab[2 * idx]     = cosf(ang);
  tab[2 * idx + 1] = sinf(ang);
}

__global__ __launch_bounds__(512, 2)
void chunked_attn_k(const float* __restrict__ Qg, const float* __restrict__ Kg,
                    const float* __restrict__ Vg, float* __restrict__ Og,
                    const float* __restrict__ tab) {
  __shared__ __align__(16) u32 lds[2 * STG];

  const int bx  = blockIdx.x;            // 512 blocks: consecutive = same (b,c)
  const int h   = bx & 15;
  const int p   = (bx >> 4) & 1;         // strip pair selector
  const int c   = (bx >> 5) & 3;
  const int b   = bx >> 7;
  const int tid = threadIdx.x;
  const int w   = tid >> 6;              // wave 0..7
  const int lane= tid & 63;
  const int l31 = lane & 31;
  const int lg2 = lane >> 5;

  const size_t cbase = (size_t)(b * Ll + c * 1024);
  const size_t hoff  = (size_t)h * 128;
  const int tb = c * 1024;

  // ---- staging registers (issued 1 tile ahead, consumed in xform) ----
  f32x2 pk[8], pva[4], pvb[4];

  auto issue = [&](int j) {
    const float* kb_ = Kg + (cbase + (size_t)j * 64) * 2048 + hoff;
    const float* vb_ = Vg + (cbase + (size_t)j * 64) * 2048 + hoff;
    #pragma unroll
    for (int r = 0; r < 8; ++r)
      pk[r] = ld_f32x2(kb_ + (size_t)(8 * w + r) * 2048 + 2 * lane);
    #pragma unroll
    for (int rp = 0; rp < 4; ++rp) {
      const float* vr = vb_ + (size_t)(8 * w + 2 * rp) * 2048 + 2 * lane;
      pva[rp] = ld_f32x2(vr);
      pvb[rp] = ld_f32x2(vr + 2048);
    }
  };

  auto xform = [&](int j, int s) {
    u32* KB = lds + s * STG;
    u32* VB = KB + KBUF;
    // cos/sin (L2/L3-hot 2MB table); lane covers d=2*lane,2*lane+1, hid=d&63
    const float* tbase = tab + (size_t)(tb + j * 64) * 128 + 4 * l31;
    f32x4 cs[8];
    #pragma unroll
    for (int r = 0; r < 8; ++r)
      cs[r] = ld_f32x4(tbase + (size_t)(8 * w + r) * 128);
    const float sgn = (lane < 32) ? -1.0f : 1.0f;  // d<64: a*c - b*s ; d>=64: b*c + a*s
    #pragma unroll
    for (int r = 0; r < 8; ++r) {
      float a0 = pk[r].x, a1 = pk[r].y;
      float p0 = __shfl_xor(a0, 32), p1 = __shfl_xor(a1, 32);
      float o0 = a0 * cs[r].x + sgn * (p0 * cs[r].y);
      float o1 = a1 * cs[r].z + sgn * (p1 * cs[r].w);
      // write banks: (2*kk + lane) % 32 -> 2-way (free)
      KB[(8 * w + r) * KSTR + lane] = packh((_Float16)o0, (_Float16)o1);
    }
    #pragma unroll
    for (int rp = 0; rp < 4; ++rp) {
      int kp = 4 * w + rp;               // k-pair column
      VB[(2 * lane) * VSTR + kp]     = packh((_Float16)pva[rp].x, (_Float16)pvb[rp].x);
      VB[(2 * lane + 1) * VSTR + kp] = packh((_Float16)pva[rp].y, (_Float16)pvb[rp].y);
    }
  };

  #pragma unroll 1
  for (int sp = 0; sp < 2; ++sp) {
    const int qs = sp ? p : (3 - p);            // heavy strip first
    const int qrow = qs * 256 + w * 32 + l31;   // chunk-local q row (lane's col)

    // ---------- Q prologue: load, rope, scale, f16 ----------
    const float* qbase = Qg + (cbase + qrow) * 2048 + hoff;
    float xq[8][8];
    #pragma unroll
    for (int ds = 0; ds < 8; ++ds) {
      const float* ptr = qbase + ds * 16 + lg2 * 8;
      f32x4 v0 = ld_f32x4(ptr);
      f32x4 v1 = ld_f32x4(ptr + 4);
      xq[ds][0]=v0.x; xq[ds][1]=v0.y; xq[ds][2]=v0.z; xq[ds][3]=v0.w;
      xq[ds][4]=v1.x; xq[ds][5]=v1.y; xq[ds][6]=v1.z; xq[ds][7]=v1.w;
    }
    const float* trowq = tab + (size_t)(tb + qrow) * 128 + lg2 * 16;
    #pragma unroll
    for (int ds = 0; ds < 4; ++ds) {
      #pragma unroll
      for (int i2 = 0; i2 < 4; ++i2) {
        f32x4 cs = ld_f32x4(trowq + ds * 32 + i2 * 4);  // c0,s0,c1,s1
        int i0 = 2 * i2;
        float a0 = xq[ds][i0],     b0 = xq[ds + 4][i0];
        xq[ds][i0]     = a0 * cs.x - b0 * cs.y;
        xq[ds + 4][i0] = b0 * cs.x + a0 * cs.y;
        float a1 = xq[ds][i0 + 1], b1 = xq[ds + 4][i0 + 1];
        xq[ds][i0 + 1]     = a1 * cs.z - b1 * cs.w;
        xq[ds + 4][i0 + 1] = b1 * cs.z + a1 * cs.w;
      }
    }
    f16x8 qh[8];
    #pragma unroll
    for (int ds = 0; ds < 8; ++ds)
      #pragma unroll
      for (int i = 0; i < 8; ++i)
        qh[ds][i] = (_Float16)(xq[ds][i] * QSCALE);

    // ---------- state ----------
    f32x16 O[4];
    #pragma unroll
    for (int n = 0; n < 4; ++n) O[n] = (f32x16)0.0f;
    float m2 = -1e30f, lsum = 0.0f;
    const int  nt    = 4 * (qs + 1);
    const int  jmaxw = 4 * qs + (w >> 1);
    const bool oddw  = w & 1;

    issue(0);
    xform(0, 0);
    __syncthreads();

    for (int j = 0; j < nt; ++j) {
      const int s = j & 1;
      const bool more = (j + 1 < nt);
      if (more) issue(j + 1);            // next-tile loads fly under compute

      if (j <= jmaxw) {
        const bool full = oddw || (j < jmaxw);  // even-wave diagonal: k-half 2 fully masked
        const u32* KB = lds + s * STG;
        const u32* VB = KB + KBUF;
        const u32* kr0 = KB + (size_t)l31 * KSTR + lg2 * 4;
        const u32* kr1 = kr0 + (size_t)32 * KSTR;

        // ---- QK^T (swapped): S^T[k][q] = K . Q^T ----
        f32x16 S0 = (f32x16)0.0f, S1 = (f32x16)0.0f;
        __builtin_amdgcn_s_setprio(1);
        #pragma unroll
        for (int ds = 0; ds < 8; ++ds) {
          S0 = MFMA(ld_frag(kr0 + ds * 8), qh[ds], S0);
          if (full) S1 = MFMA(ld_frag(kr1 + ds * 8), qh[ds], S1);
        }
        __builtin_amdgcn_s_setprio(0);

        // ---- causal mask (diagonal tile only) ----
        if (j == jmaxw) {
          #pragma unroll
          for (int r = 0; r < 16; ++r) {
            int crow = (r & 3) + 8 * (r >> 2) + 4 * lg2;
            if (crow > l31) { if (oddw) S1[r] = -1e30f; else S0[r] = -1e30f; }
          }
        }

        // ---- online softmax (base-2), T13 deferred rescale ----
        float tm = S0[0];
        #pragma unroll
        for (int r = 1; r < 16; ++r) tm = fmaxf(tm, S0[r]);
        if (full) {
          #pragma unroll
          for (int r = 0; r < 16; ++r) tm = fmaxf(tm, S1[r]);
        }
        tm = fmaxf(tm, __shfl_xor(tm, 32));
        if (!__all(tm <= m2 + 8.0f)) {
          float m2n = fmaxf(m2, tm);
          float fac = exp2f(m2 - m2n);
          lsum *= fac;
          #pragma unroll
          for (int r = 0; r < 16; ++r) {
            int rq = (r & 3) + 8 * (r >> 2) + 4 * lg2;
            float fr = __shfl(fac, rq);
            O[0][r] *= fr; O[1][r] *= fr; O[2][r] *= fr; O[3][r] *= fr;
          }
          m2 = m2n;
        }
        u32 U[16];
        float ps = 0.0f;
        #pragma unroll
        for (int t = 0; t < 8; ++t) {
          float e0 = exp2f(S0[2 * t]     - m2);
          float e1 = exp2f(S0[2 * t + 1] - m2);
          U[t] = packh((_Float16)e0, (_Float16)e1);
          ps += e0 + e1;
        }
        if (full) {
          #pragma unroll
          for (int t = 0; t < 8; ++t) {
            float e0 = exp2f(S1[2 * t]     - m2);
            float e1 = exp2f(S1[2 * t + 1] - m2);
            U[8 + t] = packh((_Float16)e0, (_Float16)e1);
            ps += e0 + e1;
          }
        }
        ps += __shfl_xor(ps, 32);
        lsum += ps;

        // ---- PV: P fragments in-register via permlane32_swap ----
        __builtin_amdgcn_s_setprio(1);
        #pragma unroll
        for (int ks = 0; ks < 4; ++ks) {
          if (ks >= 2 && !full) continue;
          u32 a0 = U[4 * ks + 0], a1 = U[4 * ks + 1];
          u32 b0 = U[4 * ks + 2], b1 = U[4 * ks + 3];
          asm("v_permlane32_swap_b32 %0, %1" : "+v"(a0), "+v"(b0));
          asm("v_permlane32_swap_b32 %0, %1" : "+v"(a1), "+v"(b1));
          u32x4 t4; t4.x = a0; t4.y = a1; t4.z = b0; t4.w = b1;
          f16x8 pa = __builtin_bit_cast(f16x8, t4);
          #pragma unroll
          for (int n = 0; n < 4; ++n) {
            // bank = (2*dv + c) % 32 -> 2-way (free)
            const u32* vp = VB + (size_t)(32 * n + l31) * VSTR + 8 * ks + 4 * lg2;
            O[n] = MFMA(pa, ld_frag(vp), O[n]);
          }
        }
        __builtin_amdgcn_s_setprio(0);
      }

      if (more) xform(j + 1, s ^ 1);
      __syncthreads();
    }

    // ---------- epilogue ----------
    float inv = 1.0f / lsum;
    #pragma unroll
    for (int r = 0; r < 16; ++r) {
      int rq = (r & 3) + 8 * (r >> 2) + 4 * lg2;
      float fi = __shfl(inv, rq);
      float* orow = Og + (cbase + qs * 256 + w * 32 + rq) * 2048 + hoff + l31;
      orow[0]  = O[0][r] * fi;
      orow[32] = O[1][r] * fi;
      orow[64] = O[2][r] * fi;
      orow[96] = O[3][r] * fi;
    }
  }
}

extern "C" void kernel_launch(void* const* d_in, const int* in_sizes, int n_in,
                              void* d_out, int out_size, void* d_ws, size_t ws_size,
                              hipStream_t stream) {
  const float* q = (const float*)d_in[0];
  const float* k = (const float*)d_in[1];
  const float* v = (const float*)d_in[2];
  const int* start = (const int*)d_in[3];
  float* out = (float*)d_out;
  float* tab = (float*)d_ws;     // 4096*64*2 floats = 2 MB

  rope_table_k<<<dim3(1024), dim3(256), 0, stream>>>(start, tab);
  chunked_attn_k<<<dim3(512), dim3(512), 0, stream>>>(q, k, v, out, tab);
}

// Round 6
// 273.513 us; speedup vs baseline: 2.2364x; 1.1543x over previous
//
#include <hip/hip_runtime.h>

// ChunkedSelfAttention (RoPE + per-chunk causal SDPA), MI355X gfx950.
// R6: prepass converts K (roped) and V^T to f16 in d_ws, stored in the
// LDS-ready XOR-swizzled layout (swizzle baked into global order, m173
// pattern). Attention kernel = R4's verified skeleton with staging reduced
// to linear 16B/lane copies; LDS reads conflict-free via col^((row&7)<<4).
// Fallback: if ws_size < 136 MB, run the R4 kernel verbatim (passed).

typedef __attribute__((ext_vector_type(2)))  float     f32x2;
typedef __attribute__((ext_vector_type(4)))  float     f32x4;
typedef __attribute__((ext_vector_type(16))) float     f32x16;
typedef __attribute__((ext_vector_type(8)))  _Float16  f16x8;
typedef unsigned int   u32;
typedef unsigned short u16;
typedef __attribute__((ext_vector_type(4))) unsigned int u32x4;

#define MFMA(a, b, c) __builtin_amdgcn_mfma_f32_32x32x16_f16(a, b, c, 0, 0, 0)

constexpr int Ll = 4096;
constexpr float QSCALE = 0.08838834764831845f * 1.4426950408889634f; // 1/sqrt(128)*log2(e)

__device__ __forceinline__ f32x4 ld_f32x4(const void* p) { f32x4 v; __builtin_memcpy(&v, p, 16); return v; }
__device__ __forceinline__ f32x2 ld_f32x2(const void* p) { f32x2 v; __builtin_memcpy(&v, p, 8);  return v; }
__device__ __forceinline__ u32x4 ld_u32x4(const void* p) { u32x4 v; __builtin_memcpy(&v, p, 16); return v; }
__device__ __forceinline__ void  st_u32x4(void* p, u32x4 v) { __builtin_memcpy(p, &v, 16); }
__device__ __forceinline__ f16x8 ld_f16x8(const void* p) { f16x8 v; __builtin_memcpy(&v, p, 16); return v; }
// 8 f16 fragment as two b64 (fallback kernel layout)
__device__ __forceinline__ f16x8 ld_frag(const u32* dwp) {
  f16x8 v;
  __builtin_memcpy(&v, dwp, 8);
  __builtin_memcpy(((char*)&v) + 8, dwp + 2, 8);
  return v;
}
__device__ __forceinline__ u32 packh(_Float16 a, _Float16 b) {
  return (u32)__builtin_bit_cast(u16, a) | ((u32)__builtin_bit_cast(u16, b) << 16);
}

// ---- cos/sin table: tab[t*128 + 2*hid] = {cos, sin}, ang = (t+start)*inv_freq ----
__global__ void rope_table_k(const int* __restrict__ startp, float* __restrict__ tab) {
  int idx = blockIdx.x * 256 + threadIdx.x;         // 4096*64 entries
  int t = idx >> 6, hid = idx & 63;
  float a = (float)hid * (-0.14391156831212878f);   // -ln(1e4)/64
  float invf = expf(a);
  float ang = (float)(t + startp[0]) * invf;
  tab[2 * idx]     = cosf(ang);
  tab[2 * idx + 1] = sinf(ang);
}

// ================= prepass: K -> roped f16, swizzled layout =================
// Kh dw layout: [GID(256)][j(16)][row(64)][o(64)], value at o = rope(K)[d, d+1]
// with d = (4*o ^ ((row&7)<<4)) >> 1  (byte-col XOR swizzle baked in).
__global__ __launch_bounds__(256)
void prep_k_kernel(const float* __restrict__ Kg, const float* __restrict__ tab,
                   u32* __restrict__ Kh) {
  const int R    = blockIdx.x * 4 + (threadIdx.x >> 6);  // k-row 0..262143
  const int lane = threadIdx.x & 63;
  const int h  = R & 15;
  const int bt = R >> 4;
  const int b  = bt >> 12;
  const int t  = bt & 4095;
  const int c  = t >> 10;
  const int j  = (t >> 6) & 15;
  const int row = t & 63;
  const int GID = (b * 4 + c) * 16 + h;
  const int sw  = (row & 7) << 4;
  const int dc  = ((4 * lane) ^ sw) >> 1;        // even
  f32x2 a = ld_f32x2(Kg + (size_t)R * 128 + dc);
  float p0 = __shfl_xor(a.x, 32);                // partner d^64 (lane^32)
  float p1 = __shfl_xor(a.y, 32);
  f32x4 cs = ld_f32x4(tab + (size_t)t * 128 + 2 * (dc & 63));
  const float sgn = (dc < 64) ? -1.0f : 1.0f;
  float o0 = a.x * cs.x + sgn * (p0 * cs.y);
  float o1 = a.y * cs.z + sgn * (p1 * cs.w);
  Kh[((size_t)(GID * 16 + j) * 64 + row) * 64 + lane] = packh((_Float16)o0, (_Float16)o1);
}

// ================= prepass: V -> V^T f16, swizzled layout =================
// VT dw layout: [GID*16+j][dv(128)][o(32)]; f16 at byte cb holds
// V[k = (cb ^ ((dv&7)<<4))>>1][dv].
__global__ __launch_bounds__(256)
void prep_vt_kernel(const float* __restrict__ Vg, u32* __restrict__ VT) {
  __shared__ __align__(16) u32 tile[4096];       // 16 KB
  const int gj  = blockIdx.x;                    // GID*16 + j
  const int GID = gj >> 4, j = gj & 15;
  const int h = GID & 15, c = (GID >> 4) & 3, b = GID >> 6;
  const int tid = threadIdx.x;
  const size_t rowbase = ((size_t)(b * 4096 + c * 1024 + j * 64)) * 16 + h;
  const int k  = tid >> 2;                       // 0..63
  const int dq = tid & 3;
  u16* t16 = (u16*)tile;
  #pragma unroll
  for (int it = 0; it < 8; ++it) {
    int dv0 = dq * 4 + 16 * it;                  // covers 0..127
    f32x4 v4 = ld_f32x4(Vg + (rowbase + (size_t)k * 16) * 128 + dv0);
    #pragma unroll
    for (int u = 0; u < 4; ++u) {
      int dv = dv0 + u;
      int ci = k ^ ((dv & 7) << 3);              // f16 index within row
      t16[dv * 64 + ci] = __builtin_bit_cast(u16, (_Float16)v4[u]);
    }
  }
  __syncthreads();
  const u32* tsrc = tile + 16 * tid;
  u32* dst = VT + (size_t)gj * 4096 + 16 * tid;
  #pragma unroll
  for (int u = 0; u < 4; ++u) st_u32x4(dst + 4 * u, ld_u32x4(tsrc + 4 * u));
}

// ================= main attention kernel (f16 staged) =================
#define ATT_STG 8192   // dwords per stage: K [64][64dw] + VT [128][32dw] = 32 KB

__global__ __launch_bounds__(512, 2)
void attn_f16_k(const float* __restrict__ Qg, const u32* __restrict__ Kh,
                const u32* __restrict__ VT, float* __restrict__ Og,
                const float* __restrict__ tab) {
  __shared__ __align__(16) u32 lds[2 * ATT_STG];  // 64 KB

  const int bx  = blockIdx.x;            // 512 blocks (R4 decode, known-pass)
  const int h   = bx & 15;
  const int p   = (bx >> 4) & 1;
  const int c   = (bx >> 5) & 3;
  const int b   = bx >> 7;
  const int tid = threadIdx.x;
  const int w   = tid >> 6;
  const int lane= tid & 63;
  const int l31 = lane & 31;
  const int lg2 = lane >> 5;

  const size_t cbase = (size_t)(b * Ll + c * 1024);
  const size_t hoff  = (size_t)h * 128;
  const int tb  = c * 1024;
  const int GID = (b * 4 + c) * 16 + h;
  const u32* khg = Kh + (size_t)GID * 16 * 4096;
  const u32* vtg = VT + (size_t)GID * 16 * 4096;

  u32x4 stg[4];
  auto issue = [&](int j) {
    #pragma unroll
    for (int i = 0; i < 4; ++i) {
      int ch = w + 8 * i;                // 32 chunks of 1 KB: 0..15 K, 16..31 VT
      const u32* src = (ch < 16) ? (khg + (size_t)j * 4096 + ch * 256 + 4 * lane)
                                 : (vtg + (size_t)j * 4096 + (ch - 16) * 256 + 4 * lane);
      stg[i] = ld_u32x4(src);
    }
  };
  auto store_stage = [&](int s) {
    u32* dst0 = lds + (size_t)s * ATT_STG;
    #pragma unroll
    for (int i = 0; i < 4; ++i) {
      int ch = w + 8 * i;
      st_u32x4(dst0 + ch * 256 + 4 * lane, stg[i]);
    }
  };

  #pragma unroll 1
  for (int sp = 0; sp < 2; ++sp) {
    const int qs = sp ? p : (3 - p);            // heavy strip first
    const int qrow = qs * 256 + w * 32 + l31;

    // ---------- Q prologue: load f32, rope, scale, f16 (verbatim R4) ----------
    const float* qbase = Qg + (cbase + qrow) * 2048 + hoff;
    float xq[8][8];
    #pragma unroll
    for (int ds = 0; ds < 8; ++ds) {
      const float* ptr = qbase + ds * 16 + lg2 * 8;
      f32x4 v0 = ld_f32x4(ptr);
      f32x4 v1 = ld_f32x4(ptr + 4);
      xq[ds][0]=v0.x; xq[ds][1]=v0.y; xq[ds][2]=v0.z; xq[ds][3]=v0.w;
      xq[ds][4]=v1.x; xq[ds][5]=v1.y; xq[ds][6]=v1.z; xq[ds][7]=v1.w;
    }
    const float* trowq = tab + (size_t)(tb + qrow) * 128 + lg2 * 16;
    #pragma unroll
    for (int ds = 0; ds < 4; ++ds) {
      #pragma unroll
      for (int i2 = 0; i2 < 4; ++i2) {
        f32x4 cs = ld_f32x4(trowq + ds * 32 + i2 * 4);
        int i0 = 2 * i2;
        float a0 = xq[ds][i0],     b0 = xq[ds + 4][i0];
        xq[ds][i0]     = a0 * cs.x - b0 * cs.y;
        xq[ds + 4][i0] = b0 * cs.x + a0 * cs.y;
        float a1 = xq[ds][i0 + 1], b1 = xq[ds + 4][i0 + 1];
        xq[ds][i0 + 1]     = a1 * cs.z - b1 * cs.w;
        xq[ds + 4][i0 + 1] = b1 * cs.z + a1 * cs.w;
      }
    }
    f16x8 qh[8];
    #pragma unroll
    for (int ds = 0; ds < 8; ++ds)
      #pragma unroll
      for (int i = 0; i < 8; ++i)
        qh[ds][i] = (_Float16)(xq[ds][i] * QSCALE);

    // ---------- state ----------
    f32x16 O[4];
    #pragma unroll
    for (int n = 0; n < 4; ++n) O[n] = (f32x16)0.0f;
    float m2 = -1e30f, lsum = 0.0f;
    const int  nt    = 4 * (qs + 1);
    const int  jmaxw = 4 * qs + (w >> 1);
    const bool oddw  = w & 1;

    issue(0);
    store_stage(0);
    __syncthreads();

    for (int j = 0; j < nt; ++j) {
      const int s = j & 1;
      const bool more = (j + 1 < nt);
      if (more) issue(j + 1);          // global loads fly under compute

      if (j <= jmaxw) {
        const bool full = oddw || (j < jmaxw);
        const u32* KB = lds + (size_t)s * ATT_STG;
        const u32* VB = KB + 4096;
        const u32* kr0 = KB + (size_t)l31 * 64;
        const u32* kr1 = kr0 + 32 * 64;
        const int  swk = (l31 & 7) << 2;      // dword-col XOR

        // ---- QK^T (swapped): S^T[k][q] = K . Q^T ----
        f32x16 S0 = (f32x16)0.0f, S1 = (f32x16)0.0f;
        __builtin_amdgcn_s_setprio(1);
        #pragma unroll
        for (int ds = 0; ds < 8; ++ds) {
          int dc = (8 * ds + 4 * lg2) ^ swk;
          S0 = MFMA(ld_f16x8(kr0 + dc), qh[ds], S0);
          if (full) S1 = MFMA(ld_f16x8(kr1 + dc), qh[ds], S1);
        }
        __builtin_amdgcn_s_setprio(0);

        // ---- causal mask (diagonal tile only) ----
        if (j == jmaxw) {
          #pragma unroll
          for (int r = 0; r < 16; ++r) {
            int crow = (r & 3) + 8 * (r >> 2) + 4 * lg2;
            if (crow > l31) { if (oddw) S1[r] = -1e30f; else S0[r] = -1e30f; }
          }
        }

        // ---- online softmax (base-2), T13 deferred rescale ----
        float tm = S0[0];
        #pragma unroll
        for (int r = 1; r < 16; ++r) tm = fmaxf(tm, S0[r]);
        if (full) {
          #pragma unroll
          for (int r = 0; r < 16; ++r) tm = fmaxf(tm, S1[r]);
        }
        tm = fmaxf(tm, __shfl_xor(tm, 32));
        if (!__all(tm <= m2 + 8.0f)) {
          float m2n = fmaxf(m2, tm);
          float fac = exp2f(m2 - m2n);
          lsum *= fac;
          #pragma unroll
          for (int r = 0; r < 16; ++r) {
            int rq = (r & 3) + 8 * (r >> 2) + 4 * lg2;
            float fr = __shfl(fac, rq);
            O[0][r] *= fr; O[1][r] *= fr; O[2][r] *= fr; O[3][r] *= fr;
          }
          m2 = m2n;
        }
        u32 U[16];
        float ps = 0.0f;
        #pragma unroll
        for (int t = 0; t < 8; ++t) {
          float e0 = exp2f(S0[2 * t]     - m2);
          float e1 = exp2f(S0[2 * t + 1] - m2);
          U[t] = packh((_Float16)e0, (_Float16)e1);
          ps += e0 + e1;
        }
        if (full) {
          #pragma unroll
          for (int t = 0; t < 8; ++t) {
            float e0 = exp2f(S1[2 * t]     - m2);
            float e1 = exp2f(S1[2 * t + 1] - m2);
            U[8 + t] = packh((_Float16)e0, (_Float16)e1);
            ps += e0 + e1;
          }
        }
        ps += __shfl_xor(ps, 32);
        lsum += ps;

        // ---- PV: P fragments in-register via permlane32_swap ----
        __builtin_amdgcn_s_setprio(1);
        #pragma unroll
        for (int ks = 0; ks < 4; ++ks) {
          if (ks >= 2 && !full) continue;
          u32 a0 = U[4 * ks + 0], a1 = U[4 * ks + 1];
          u32 b0 = U[4 * ks + 2], b1 = U[4 * ks + 3];
          asm("v_permlane32_swap_b32 %0, %1" : "+v"(a0), "+v"(b0));
          asm("v_permlane32_swap_b32 %0, %1" : "+v"(a1), "+v"(b1));
          u32x4 t4; t4.x = a0; t4.y = a1; t4.z = b0; t4.w = b1;
          f16x8 pa = __builtin_bit_cast(f16x8, t4);
          int dcv = (8 * ks + 4 * lg2) ^ swk;
          #pragma unroll
          for (int n = 0; n < 4; ++n) {
            O[n] = MFMA(pa, ld_f16x8(VB + (size_t)(32 * n + l31) * 32 + dcv), O[n]);
          }
        }
        __builtin_amdgcn_s_setprio(0);
      }

      if (more) store_stage(s ^ 1);
      __syncthreads();
    }

    // ---------- epilogue ----------
    float inv = 1.0f / lsum;
    #pragma unroll
    for (int r = 0; r < 16; ++r) {
      int rq = (r & 3) + 8 * (r >> 2) + 4 * lg2;
      float fi = __shfl(inv, rq);
      float* orow = Og + (cbase + qs * 256 + w * 32 + rq) * 2048 + hoff + l31;
      orow[0]  = O[0][r] * fi;
      orow[32] = O[1][r] * fi;
      orow[64] = O[2][r] * fi;
      orow[96] = O[3][r] * fi;
    }
  }
}

// ================= fallback: R4 kernel verbatim (passed) =================
#define KSTR 66
#define VSTR 34
#define KBUF (64 * KSTR)
#define VBUF (128 * VSTR)
#define STG  (KBUF + VBUF)

__global__ __launch_bounds__(512, 2)
void chunked_attn_fb(const float* __restrict__ Qg, const float* __restrict__ Kg,
                     const float* __restrict__ Vg, float* __restrict__ Og,
                     const float* __restrict__ tab) {
  __shared__ __align__(16) u32 lds[2 * STG];

  const int bx  = blockIdx.x;
  const int h   = bx & 15;
  const int p   = (bx >> 4) & 1;
  const int c   = (bx >> 5) & 3;
  const int b   = bx >> 7;
  const int tid = threadIdx.x;
  const int w   = tid >> 6;
  const int lane= tid & 63;
  const int l31 = lane & 31;
  const int lg2 = lane >> 5;

  const size_t cbase = (size_t)(b * Ll + c * 1024);
  const size_t hoff  = (size_t)h * 128;
  const int tb = c * 1024;

  f32x2 pk[8], pva[4], pvb[4];

  auto issue = [&](int j) {
    const float* kb_ = Kg + (cbase + (size_t)j * 64) * 2048 + hoff;
    const float* vb_ = Vg + (cbase + (size_t)j * 64) * 2048 + hoff;
    #pragma unroll
    for (int r = 0; r < 8; ++r)
      pk[r] = ld_f32x2(kb_ + (size_t)(8 * w + r) * 2048 + 2 * lane);
    #pragma unroll
    for (int rp = 0; rp < 4; ++rp) {
      const float* vr = vb_ + (size_t)(8 * w + 2 * rp) * 2048 + 2 * lane;
      pva[rp] = ld_f32x2(vr);
      pvb[rp] = ld_f32x2(vr + 2048);
    }
  };

  auto xform = [&](int j, int s) {
    u32* KB = lds + s * STG;
    u32* VB = KB + KBUF;
    const float* tbase = tab + (size_t)(tb + j * 64) * 128 + 4 * l31;
    f32x4 cs[8];
    #pragma unroll
    for (int r = 0; r < 8; ++r)
      cs[r] = ld_f32x4(tbase + (size_t)(8 * w + r) * 128);
    const float sgn = (lane < 32) ? -1.0f : 1.0f;
    #pragma unroll
    for (int r = 0; r < 8; ++r) {
      float a0 = pk[r].x, a1 = pk[r].y;
      float p0 = __shfl_xor(a0, 32), p1 = __shfl_xor(a1, 32);
      float o0 = a0 * cs[r].x + sgn * (p0 * cs[r].y);
      float o1 = a1 * cs[r].z + sgn * (p1 * cs[r].w);
      KB[(8 * w + r) * KSTR + lane] = packh((_Float16)o0, (_Float16)o1);
    }
    #pragma unroll
    for (int rp = 0; rp < 4; ++rp) {
      int kp = 4 * w + rp;
      VB[(2 * lane) * VSTR + kp]     = packh((_Float16)pva[rp].x, (_Float16)pvb[rp].x);
      VB[(2 * lane + 1) * VSTR + kp] = packh((_Float16)pva[rp].y, (_Float16)pvb[rp].y);
    }
  };

  #pragma unroll 1
  for (int sp = 0; sp < 2; ++sp) {
    const int qs = sp ? p : (3 - p);
    const int qrow = qs * 256 + w * 32 + l31;

    const float* qbase = Qg + (cbase + qrow) * 2048 + hoff;
    float xq[8][8];
    #pragma unroll
    for (int ds = 0; ds < 8; ++ds) {
      const float* ptr = qbase + ds * 16 + lg2 * 8;
      f32x4 v0 = ld_f32x4(ptr);
      f32x4 v1 = ld_f32x4(ptr + 4);
      xq[ds][0]=v0.x; xq[ds][1]=v0.y; xq[ds][2]=v0.z; xq[ds][3]=v0.w;
      xq[ds][4]=v1.x; xq[ds][5]=v1.y; xq[ds][6]=v1.z; xq[ds][7]=v1.w;
    }
    const float* trowq = tab + (size_t)(tb + qrow) * 128 + lg2 * 16;
    #pragma unroll
    for (int ds = 0; ds < 4; ++ds) {
      #pragma unroll
      for (int i2 = 0; i2 < 4; ++i2) {
        f32x4 cs = ld_f32x4(trowq + ds * 32 + i2 * 4);
        int i0 = 2 * i2;
        float a0 = xq[ds][i0],     b0 = xq[ds + 4][i0];
        xq[ds][i0]     = a0 * cs.x - b0 * cs.y;
        xq[ds + 4][i0] = b0 * cs.x + a0 * cs.y;
        float a1 = xq[ds][i0 + 1], b1 = xq[ds + 4][i0 + 1];
        xq[ds][i0 + 1]     = a1 * cs.z - b1 * cs.w;
        xq[ds + 4][i0 + 1] = b1 * cs.z + a1 * cs.w;
      }
    }
    f16x8 qh[8];
    #pragma unroll
    for (int ds = 0; ds < 8; ++ds)
      #pragma unroll
      for (int i = 0; i < 8; ++i)
        qh[ds][i] = (_Float16)(xq[ds][i] * QSCALE);

    f32x16 O[4];
    #pragma unroll
    for (int n = 0; n < 4; ++n) O[n] = (f32x16)0.0f;
    float m2 = -1e30f, lsum = 0.0f;
    const int  nt    = 4 * (qs + 1);
    const int  jmaxw = 4 * qs + (w >> 1);
    const bool oddw  = w & 1;

    issue(0);
    xform(0, 0);
    __syncthreads();

    for (int j = 0; j < nt; ++j) {
      const int s = j & 1;
      const bool more = (j + 1 < nt);
      if (more) issue(j + 1);

      if (j <= jmaxw) {
        const bool full = oddw || (j < jmaxw);
        const u32* KB = lds + s * STG;
        const u32* VB = KB + KBUF;
        const u32* kr0 = KB + (size_t)l31 * KSTR + lg2 * 4;
        const u32* kr1 = kr0 + (size_t)32 * KSTR;

        f32x16 S0 = (f32x16)0.0f, S1 = (f32x16)0.0f;
        __builtin_amdgcn_s_setprio(1);
        #pragma unroll
        for (int ds = 0; ds < 8; ++ds) {
          S0 = MFMA(ld_frag(kr0 + ds * 8), qh[ds], S0);
          if (full) S1 = MFMA(ld_frag(kr1 + ds * 8), qh[ds], S1);
        }
        __builtin_amdgcn_s_setprio(0);

        if (j == jmaxw) {
          #pragma unroll
          for (int r = 0; r < 16; ++r) {
            int crow = (r & 3) + 8 * (r >> 2) + 4 * lg2;
            if (crow > l31) { if (oddw) S1[r] = -1e30f; else S0[r] = -1e30f; }
          }
        }

        float tm = S0[0];
        #pragma unroll
        for (int r = 1; r < 16; ++r) tm = fmaxf(tm, S0[r]);
        if (full) {
          #pragma unroll
          for (int r = 0; r < 16; ++r) tm = fmaxf(tm, S1[r]);
        }
        tm = fmaxf(tm, __shfl_xor(tm, 32));
        if (!__all(tm <= m2 + 8.0f)) {
          float m2n = fmaxf(m2, tm);
          float fac = exp2f(m2 - m2n);
          lsum *= fac;
          #pragma unroll
          for (int r = 0; r < 16; ++r) {
            int rq = (r & 3) + 8 * (r >> 2) + 4 * lg2;
            float fr = __shfl(fac, rq);
            O[0][r] *= fr; O[1][r] *= fr; O[2][r] *= fr; O[3][r] *= fr;
          }
          m2 = m2n;
        }
        u32 U[16];
        float ps = 0.0f;
        #pragma unroll
        for (int t = 0; t < 8; ++t) {
          float e0 = exp2f(S0[2 * t]     - m2);
          float e1 = exp2f(S0[2 * t + 1] - m2);
          U[t] = packh((_Float16)e0, (_Float16)e1);
          ps += e0 + e1;
        }
        if (full) {
          #pragma unroll
          for (int t = 0; t < 8; ++t) {
            float e0 = exp2f(S1[2 * t]     - m2);
            float e1 = exp2f(S1[2 * t + 1] - m2);
            U[8 + t] = packh((_Float16)e0, (_Float16)e1);
            ps += e0 + e1;
          }
        }
        ps += __shfl_xor(ps, 32);
        lsum += ps;

        __builtin_amdgcn_s_setprio(1);
        #pragma unroll
        for (int ks = 0; ks < 4; ++ks) {
          if (ks >= 2 && !full) continue;
          u32 a0 = U[4 * ks + 0], a1 = U[4 * ks + 1];
          u32 b0 = U[4 * ks + 2], b1 = U[4 * ks + 3];
          asm("v_permlane32_swap_b32 %0, %1" : "+v"(a0), "+v"(b0));
          asm("v_permlane32_swap_b32 %0, %1" : "+v"(a1), "+v"(b1));
          u32x4 t4; t4.x = a0; t4.y = a1; t4.z = b0; t4.w = b1;
          f16x8 pa = __builtin_bit_cast(f16x8, t4);
          #pragma unroll
          for (int n = 0; n < 4; ++n) {
            const u32* vp = VB + (size_t)(32 * n + l31) * VSTR + 8 * ks + 4 * lg2;
            O[n] = MFMA(pa, ld_frag(vp), O[n]);
          }
        }
        __builtin_amdgcn_s_setprio(0);
      }

      if (more) xform(j + 1, s ^ 1);
      __syncthreads();
    }

    float inv = 1.0f / lsum;
    #pragma unroll
    for (int r = 0; r < 16; ++r) {
      int rq = (r & 3) + 8 * (r >> 2) + 4 * lg2;
      float fi = __shfl(inv, rq);
      float* orow = Og + (cbase + qs * 256 + w * 32 + rq) * 2048 + hoff + l31;
      orow[0]  = O[0][r] * fi;
      orow[32] = O[1][r] * fi;
      orow[64] = O[2][r] * fi;
      orow[96] = O[3][r] * fi;
    }
  }
}

extern "C" void kernel_launch(void* const* d_in, const int* in_sizes, int n_in,
                              void* d_out, int out_size, void* d_ws, size_t ws_size,
                              hipStream_t stream) {
  const float* q = (const float*)d_in[0];
  const float* k = (const float*)d_in[1];
  const float* v = (const float*)d_in[2];
  const int* start = (const int*)d_in[3];
  float* out = (float*)d_out;

  float* tab = (float*)d_ws;                          // 2 MB
  const size_t KH_OFFB = 2u * 1024 * 1024;            // 64 MB
  const size_t VT_OFFB = KH_OFFB + 64u * 1024 * 1024; // 64 MB
  const size_t NEED = VT_OFFB + 64u * 1024 * 1024;    // 130 MB total

  rope_table_k<<<dim3(1024), dim3(256), 0, stream>>>(start, tab);

  if (ws_size >= NEED) {
    u32* Kh = (u32*)((char*)d_ws + KH_OFFB);
    u32* VT = (u32*)((char*)d_ws + VT_OFFB);
    prep_k_kernel<<<dim3(65536), dim3(256), 0, stream>>>(k, tab, Kh);
    prep_vt_kernel<<<dim3(4096), dim3(256), 0, stream>>>(v, VT);
    attn_f16_k<<<dim3(512), dim3(512), 0, stream>>>(q, Kh, VT, out, tab);
  } else {
    chunked_attn_fb<<<dim3(512), dim3(512), 0, stream>>>(q, k, v, out, tab);
  }
}